// Round 14
// baseline (212.518 us; speedup 1.0000x reference)
//
#include <hip/hip_runtime.h>
#include <hip/hip_bf16.h>
#include <cstdint>

#define B_ROWS 4096
#define DIM 1024
#define NN 8192  // 2*B

typedef float f32x4 __attribute__((ext_vector_type(4)));
typedef float f32x16 __attribute__((ext_vector_type(16)));
typedef int v4i __attribute__((ext_vector_type(4)));
typedef int v8i __attribute__((ext_vector_type(8)));

__device__ __forceinline__ float wave_reduce_sum(float v) {
    v += __shfl_xor(v, 1);
    v += __shfl_xor(v, 2);
    v += __shfl_xor(v, 4);
    v += __shfl_xor(v, 8);
    v += __shfl_xor(v, 16);
    v += __shfl_xor(v, 32);
    return v;
}

__device__ __forceinline__ void gld_lds16(const void* g, void* l) {
    __builtin_amdgcn_global_load_lds(
        (__attribute__((address_space(1))) void*)(uintptr_t)g,
        (__attribute__((address_space(3))) void*)l, 16, 0, 0);
}

// fp32 -> OCP e4m3fn, round-to-nearest-even. Inputs here satisfy |x| < 0.5,
// so no overflow/NaN handling needed. Subnormal cutoff at 2^-6.
__device__ __forceinline__ unsigned char f32_to_e4m3(float x) {
    unsigned int b = __float_as_uint(x);
    unsigned int sign = (b >> 24) & 0x80u;
    unsigned int ab = b & 0x7FFFFFFFu;
    unsigned int out;
    if (__uint_as_float(ab) >= 0.015625f) {
        unsigned int rb = ab + 0x7FFFFu + ((ab >> 20) & 1u);  // RNE at 3 mantissa bits
        int E = (int)(rb >> 23) - 127;
        out = (unsigned int)((E + 7) << 3) | ((rb >> 20) & 7u);
    } else {
        out = (unsigned int)rintf(__uint_as_float(ab) * 512.0f);  // subnormal, 0..8
    }
    return (unsigned char)(out | sign);
}

// Kernel 1: L2-normalize + positives, ONE WAVE PER ROW-PAIR. No LDS/barriers.
__global__ void norm_pos_kernel(const float* __restrict__ p1,
                                const float* __restrict__ p2,
                                unsigned char* __restrict__ rep,
                                float* __restrict__ pos) {
    const int wv = threadIdx.x >> 6, lane = threadIdx.x & 63;
    const int i = blockIdx.x * 4 + wv;  // 0..4095
    const float4* ap = (const float4*)(p1 + (size_t)i * DIM);
    const float4* bp = (const float4*)(p2 + (size_t)i * DIM);
    float4 a[4], b[4];
#pragma unroll
    for (int c = 0; c < 4; ++c) { a[c] = ap[lane + 64 * c]; b[c] = bp[lane + 64 * c]; }
    float s1 = 0.f, s2 = 0.f, dp = 0.f;
#pragma unroll
    for (int c = 0; c < 4; ++c) {
        s1 += a[c].x * a[c].x + a[c].y * a[c].y + a[c].z * a[c].z + a[c].w * a[c].w;
        s2 += b[c].x * b[c].x + b[c].y * b[c].y + b[c].z * b[c].z + b[c].w * b[c].w;
        dp += a[c].x * b[c].x + a[c].y * b[c].y + a[c].z * b[c].z + a[c].w * b[c].w;
    }
    s1 = wave_reduce_sum(s1);
    s2 = wave_reduce_sum(s2);
    dp = wave_reduce_sum(dp);
    const float sc1 = rsqrtf(s1), sc2 = rsqrtf(s2);
    uchar4* o1 = (uchar4*)(rep + (size_t)i * DIM);
    uchar4* o2 = (uchar4*)(rep + (size_t)(i + B_ROWS) * DIM);
#pragma unroll
    for (int c = 0; c < 4; ++c) {
        uchar4 u1, u2;
        u1.x = f32_to_e4m3(a[c].x * sc1); u1.y = f32_to_e4m3(a[c].y * sc1);
        u1.z = f32_to_e4m3(a[c].z * sc1); u1.w = f32_to_e4m3(a[c].w * sc1);
        u2.x = f32_to_e4m3(b[c].x * sc2); u2.y = f32_to_e4m3(b[c].y * sc2);
        u2.z = f32_to_e4m3(b[c].z * sc2); u2.w = f32_to_e4m3(b[c].w * sc2);
        o1[lane + 64 * c] = u1;
        o2[lane + 64 * c] = u2;
    }
    if (lane == 0) pos[i] = dp * sc1 * sc2;
}

// Kernel 2: symmetric fused GEMM, MX-scaled fp8 (unit scales 2^0), shape
// 32x32x64 f8f6f4. Upper-triangle tiles (rb<=cb), BK=64, 2x2 waves; each
// wave = 64x64 via 2x2 frags of 32x32 -> acc 2x2 x f32x16 = 64 VGPR,
// af/bf 2 x v8i = 32 -> ~96 live (R8's spill was acc[4][4]+8xv8i = 128).
// LDS traffic per iter: 8 ds_read_b128/wave — IDENTICAL to R7; MFMA
// demand/CU drops 81k -> 36k cyc (MX 32x32 rate, m59: 4686 TF).
//
// Staging (R7-proven): thread t -> row t>>2, global 16B seg (t&3)^((row>>1)&3);
// per-quad one 64 B run (coalesced); LDS slot forced to t*16; reader XOR
// undoes the swizzle so every lane holds TRUE global k-segs.
// A-operand (32x32x64): lane (m=l&31, kh=l>>5) holds k-bytes kh*32..+32
// as v8i = [slot 2kh][slot 2kh+1] (same family rule HW-verified via R8's
// 16x16x128 passing absmax 0). A and B lanes with equal kh carry the same
// k-range -> contraction consistent.
__global__ __launch_bounds__(256) void gemm_kernel(const unsigned char* __restrict__ rep,
                                                   float* __restrict__ partial) {
    // rb-major triangle decode: start(rb) = 64*rb - rb*(rb-1)/2
    const int bid = blockIdx.x;
    int rb = (int)(64.5f - sqrtf(4160.25f - 2.0f * (float)bid));
    while (64 * (rb + 1) - (rb + 1) * rb / 2 <= bid) ++rb;
    while (64 * rb - rb * (rb - 1) / 2 > bid) --rb;
    const int cb = rb + (bid - (64 * rb - rb * (rb - 1) / 2));

    __shared__ __align__(16) unsigned char As[8192];  // 8 KB: 128 rows x 64 B
    __shared__ __align__(16) unsigned char Bs[8192];  // 8 KB
    const int t = threadIdx.x;
    const int lane = t & 63;
    const int wv = t >> 6;     // 0..3
    const int wr = wv >> 1;    // wave row-half
    const int wc = wv & 1;     // wave col-half
    const int m = lane & 31;   // frag m,n index (32-row)
    const int kh = lane >> 5;  // frag k-half (32 B)

    // staging source (unchanged from R7)
    const int sr = t >> 2;
    const int sg = (t & 3) ^ ((sr >> 1) & 3);
    const unsigned char* aS = rep + (size_t)(rb * 128 + sr) * DIM + sg * 16;
    const unsigned char* bS = rep + (size_t)(cb * 128 + sr) * DIM + sg * 16;
    unsigned char* aD = As + t * 16;  // HW-forced: wave-uniform base + lane*16
    unsigned char* bD = Bs + t * 16;

    // fragment read offsets (k-invariant): row m within 64-row group, 64 B/row;
    // swizzled slots s0 = (2kh)^fsw, s1 = (2kh+1)^fsw with fsw = (m>>1)&3
    // (mi*32 doesn't change fsw since 32>>1 = 16 ≡ 0 mod 4).
    const int fsw = (m >> 1) & 3;
    const int s0 = ((2 * kh) ^ fsw) << 4;
    const int s1 = ((2 * kh + 1) ^ fsw) << 4;
    const unsigned char* aF = As + wr * 4096 + m * 64;
    const unsigned char* bF = Bs + wc * 4096 + m * 64;

    f32x16 acc[2][2];
#pragma unroll
    for (int i = 0; i < 2; ++i)
#pragma unroll
        for (int j = 0; j < 2; ++j)
#pragma unroll
            for (int e = 0; e < 16; ++e) acc[i][j][e] = 0.f;

    for (int kk = 0; kk < DIM / 64; ++kk) {
        const unsigned char* a0 = aS + kk * 64;
        const unsigned char* b0 = bS + kk * 64;
        gld_lds16(a0, aD);                            // A rows 0..63
        gld_lds16(a0 + (size_t)64 * DIM, aD + 4096);  // A rows 64..127
        gld_lds16(b0, bD);
        gld_lds16(b0 + (size_t)64 * DIM, bD + 4096);
        __syncthreads();

        v8i af[2], bf[2];
#pragma unroll
        for (int mi = 0; mi < 2; ++mi) {
            v4i lo = *(const v4i*)(aF + mi * 2048 + s0);
            v4i hi = *(const v4i*)(aF + mi * 2048 + s1);
            af[mi] = __builtin_shufflevector(lo, hi, 0, 1, 2, 3, 4, 5, 6, 7);
        }
#pragma unroll
        for (int ni = 0; ni < 2; ++ni) {
            v4i lo = *(const v4i*)(bF + ni * 2048 + s0);
            v4i hi = *(const v4i*)(bF + ni * 2048 + s1);
            bf[ni] = __builtin_shufflevector(lo, hi, 0, 1, 2, 3, 4, 5, 6, 7);
        }
#pragma unroll
        for (int mi = 0; mi < 2; ++mi)
#pragma unroll
            for (int ni = 0; ni < 2; ++ni)
                acc[mi][ni] = __builtin_amdgcn_mfma_scale_f32_32x32x64_f8f6f4(
                    af[mi], bf[ni], acc[mi][ni],
                    0, 0,               // cbsz=0 (fp8 e4m3), blgp=0 (fp8 e4m3)
                    0, 0x7F7F7F7F,      // op_sel_a, scale_a = 2^0 (E8M0 127)
                    0, 0x7F7F7F7F);     // op_sel_b, scale_b = 2^0
        __syncthreads();
    }

    // Epilogue. 32x32 C/D layout (m74/m101, shape-determined):
    //   col = ni*32 + (lane&31), row = mi*32 + (reg&3) + 8*(reg>>2) + 4*kh.
    // Row-partials -> slot 2*cb+wc; transpose col-partials -> slot 2*rb+wr.
    // Row r of block i receives slots {2c,2c+1 : c>=i} ∪ {2c,2c+1 : c<i} = all 128, disjoint.
    float colsum[2];
    colsum[0] = 0.f;
    colsum[1] = 0.f;

#pragma unroll
    for (int mi = 0; mi < 2; ++mi) {
#pragma unroll
        for (int reg = 0; reg < 16; ++reg) {
            const int r32 = (reg & 3) + 8 * (reg >> 2) + 4 * kh;
            const int grow = rb * 128 + wr * 64 + mi * 32 + r32;
            float rs = 0.f;
#pragma unroll
            for (int ni = 0; ni < 2; ++ni) {
                const int gcol = cb * 128 + wc * 64 + ni * 32 + m;
                const float e =
                    (grow == gcol) ? 0.f : __expf(acc[mi][ni][reg] * 2.0f);  // 1/T=2
                rs += e;
                colsum[ni] += e;
            }
            rs += __shfl_xor(rs, 1);
            rs += __shfl_xor(rs, 2);
            rs += __shfl_xor(rs, 4);
            rs += __shfl_xor(rs, 8);
            rs += __shfl_xor(rs, 16);
            if (m == 0) partial[(size_t)(2 * cb + wc) * NN + grow] = rs;
        }
    }

    if (rb != cb) {
#pragma unroll
        for (int ni = 0; ni < 2; ++ni)
            colsum[ni] += __shfl_xor(colsum[ni], 32);  // fold kh -> all 64 rows
        if (kh == 0) {
#pragma unroll
            for (int ni = 0; ni < 2; ++ni)
                partial[(size_t)(2 * rb + wr) * NN + cb * 128 + wc * 64 + ni * 32 + m] =
                    colsum[ni];
        }
    }
}

// Kernel 3: per-row denom -> per-row loss -> 64 block sums. 2 threads/row.
__global__ void reduce_rows_kernel(const float* __restrict__ partial,
                                   const float* __restrict__ pos,
                                   float* __restrict__ bsum) {
    const int g = blockIdx.x * 256 + threadIdx.x;  // 64 x 256 = 16384
    const int r = g >> 1;
    const int half = g & 1;
    float s0 = 0.f, s1 = 0.f, s2 = 0.f, s3 = 0.f;
    for (int kb = half * 64; kb < half * 64 + 64; kb += 4) {
        s0 += partial[(size_t)(kb + 0) * NN + r];
        s1 += partial[(size_t)(kb + 1) * NN + r];
        s2 += partial[(size_t)(kb + 2) * NN + r];
        s3 += partial[(size_t)(kb + 3) * NN + r];
    }
    float s = (s0 + s1) + (s2 + s3);
    s += __shfl_xor(s, 1);  // both lanes of the pair hold the full row sum
    float v = __logf(s) - pos[r & (B_ROWS - 1)] * 2.0f;  // counted twice; *0.5 below
    v = wave_reduce_sum(v);
    __shared__ float red[4];
    const int lane = threadIdx.x & 63, wv = threadIdx.x >> 6;
    if (lane == 0) red[wv] = v;
    __syncthreads();
    if (threadIdx.x == 0)
        bsum[blockIdx.x] = (red[0] + red[1] + red[2] + red[3]) * 0.5f;
}

// Kernel 4: final scalar
__global__ void final_kernel(const float* __restrict__ bsum,
                             float* __restrict__ out) {
    float s = bsum[threadIdx.x];
    s = wave_reduce_sum(s);
    if (threadIdx.x == 0) out[0] = s * (1.0f / NN);
}

extern "C" void kernel_launch(void* const* d_in, const int* in_sizes, int n_in,
                              void* d_out, int out_size, void* d_ws, size_t ws_size,
                              hipStream_t stream) {
    const float* p1 = (const float*)d_in[0];
    const float* p2 = (const float*)d_in[1];
    char* ws = (char*)d_ws;
    unsigned char* rep = (unsigned char*)ws;                  // 8 MiB (fp8)
    float* partial = (float*)(ws + (size_t)8 * 1024 * 1024);  // 4 MiB (128 x 8192)
    float* pos = (float*)(ws + (size_t)12 * 1024 * 1024);     // 16 KiB
    float* bsum = (float*)(ws + (size_t)12 * 1024 * 1024 + 16384);  // 256 B
    float* out = (float*)d_out;

    norm_pos_kernel<<<1024, 256, 0, stream>>>(p1, p2, rep, pos);
    gemm_kernel<<<2080, 256, 0, stream>>>(rep, partial);
    reduce_rows_kernel<<<64, 256, 0, stream>>>(partial, pos, bsum);
    final_kernel<<<1, 64, 0, stream>>>(bsum, out);
}

// Round 15
// 156.554 us; speedup vs baseline: 1.3575x; 1.3575x over previous
//
#include <hip/hip_runtime.h>
#include <hip/hip_bf16.h>
#include <cstdint>

#define B_ROWS 4096
#define DIM 1024
#define NN 8192  // 2*B

typedef float f32x16 __attribute__((ext_vector_type(16)));
typedef long lx2 __attribute__((ext_vector_type(2)));

__device__ __forceinline__ float wave_reduce_sum(float v) {
    v += __shfl_xor(v, 1);
    v += __shfl_xor(v, 2);
    v += __shfl_xor(v, 4);
    v += __shfl_xor(v, 8);
    v += __shfl_xor(v, 16);
    v += __shfl_xor(v, 32);
    return v;
}

__device__ __forceinline__ void gld_lds16(const void* g, void* l) {
    __builtin_amdgcn_global_load_lds(
        (__attribute__((address_space(1))) void*)(uintptr_t)g,
        (__attribute__((address_space(3))) void*)l, 16, 0, 0);
}

// fp32 -> OCP e4m3fn, round-to-nearest-even. Inputs here satisfy |x| < 0.5,
// so no overflow/NaN handling needed. Subnormal cutoff at 2^-6.
__device__ __forceinline__ unsigned char f32_to_e4m3(float x) {
    unsigned int b = __float_as_uint(x);
    unsigned int sign = (b >> 24) & 0x80u;
    unsigned int ab = b & 0x7FFFFFFFu;
    unsigned int out;
    if (__uint_as_float(ab) >= 0.015625f) {
        unsigned int rb = ab + 0x7FFFFu + ((ab >> 20) & 1u);  // RNE at 3 mantissa bits
        int E = (int)(rb >> 23) - 127;
        out = (unsigned int)((E + 7) << 3) | ((rb >> 20) & 7u);
    } else {
        out = (unsigned int)rintf(__uint_as_float(ab) * 512.0f);  // subnormal, 0..8
    }
    return (unsigned char)(out | sign);
}

// Kernel 1: L2-normalize + positives, ONE WAVE PER ROW-PAIR. No LDS/barriers.
__global__ void norm_pos_kernel(const float* __restrict__ p1,
                                const float* __restrict__ p2,
                                unsigned char* __restrict__ rep,
                                float* __restrict__ pos) {
    const int wv = threadIdx.x >> 6, lane = threadIdx.x & 63;
    const int i = blockIdx.x * 4 + wv;  // 0..4095
    const float4* ap = (const float4*)(p1 + (size_t)i * DIM);
    const float4* bp = (const float4*)(p2 + (size_t)i * DIM);
    float4 a[4], b[4];
#pragma unroll
    for (int c = 0; c < 4; ++c) { a[c] = ap[lane + 64 * c]; b[c] = bp[lane + 64 * c]; }
    float s1 = 0.f, s2 = 0.f, dp = 0.f;
#pragma unroll
    for (int c = 0; c < 4; ++c) {
        s1 += a[c].x * a[c].x + a[c].y * a[c].y + a[c].z * a[c].z + a[c].w * a[c].w;
        s2 += b[c].x * b[c].x + b[c].y * b[c].y + b[c].z * b[c].z + b[c].w * b[c].w;
        dp += a[c].x * b[c].x + a[c].y * b[c].y + a[c].z * b[c].z + a[c].w * b[c].w;
    }
    s1 = wave_reduce_sum(s1);
    s2 = wave_reduce_sum(s2);
    dp = wave_reduce_sum(dp);
    const float sc1 = rsqrtf(s1), sc2 = rsqrtf(s2);
    uchar4* o1 = (uchar4*)(rep + (size_t)i * DIM);
    uchar4* o2 = (uchar4*)(rep + (size_t)(i + B_ROWS) * DIM);
#pragma unroll
    for (int c = 0; c < 4; ++c) {
        uchar4 u1, u2;
        u1.x = f32_to_e4m3(a[c].x * sc1); u1.y = f32_to_e4m3(a[c].y * sc1);
        u1.z = f32_to_e4m3(a[c].z * sc1); u1.w = f32_to_e4m3(a[c].w * sc1);
        u2.x = f32_to_e4m3(b[c].x * sc2); u2.y = f32_to_e4m3(b[c].y * sc2);
        u2.z = f32_to_e4m3(b[c].z * sc2); u2.w = f32_to_e4m3(b[c].w * sc2);
        o1[lane + 64 * c] = u1;
        o2[lane + 64 * c] = u2;
    }
    if (lane == 0) pos[i] = dp * sc1 * sc2;
}

// Kernel 2: symmetric fused GEMM, fp8 e4m3 via NON-SCALED 32x32x16 MFMA
// (plain `long` operands — the mfma_scale builtin inflated VGPR to 232 in
// R8/R14; off the table). Upper-triangle tiles (rb<=cb), BK=128, 2x2 waves;
// each wave = 64x64 via 2x2 frags of 32x32: acc = 2x2 x f32x16 = 64 regs.
// 16 barriers total (vs R7's 32) — attacks the measured barrier-drain gap.
//
// LDS: 128 rows x 128 B per operand (16 KB each, 32 KB/block). Row rl's
// eight 16 B slots are XOR-swizzled by (rl>>1)&7. Staging call c: thread t
// -> row rl = c*32 + t>>3, global slot (t&7)^((rl>>1)&7); per 8-lane octet
// one contiguous 128 B global run (coalesced); LDS dest = c*4096 + t*16
// (global_load_lds HW constraint). Reader XOR-undoes the swizzle.
//
// K-perm trick (R7-proven, generalized): lane (m = l&31, kh = l>>5) reads
// b128 slot gs = p*4 + 2r + kh (p = K-half phase, r = 0,1); MFMA (r,h) uses
// half h of that slot. Lanes kh=0/kh=1 jointly cover 16 distinct global k
// per MFMA, identically for A and B -> contraction invariant. Bank pattern
// per 16-lane quantum: banks 4s..4s+3, exact 2-way aliasing (free, m136).
// 32x32 C/D layout + epilogue verified on HW by R14 (absmax 0.0).
__global__ __launch_bounds__(256) void gemm_kernel(const unsigned char* __restrict__ rep,
                                                   float* __restrict__ partial) {
    // rb-major triangle decode: start(rb) = 64*rb - rb*(rb-1)/2
    const int bid = blockIdx.x;
    int rb = (int)(64.5f - sqrtf(4160.25f - 2.0f * (float)bid));
    while (64 * (rb + 1) - (rb + 1) * rb / 2 <= bid) ++rb;
    while (64 * rb - rb * (rb - 1) / 2 > bid) --rb;
    const int cb = rb + (bid - (64 * rb - rb * (rb - 1) / 2));

    __shared__ __align__(16) unsigned char As[16384];  // 128 rows x 128 B
    __shared__ __align__(16) unsigned char Bs[16384];
    const int t = threadIdx.x;
    const int lane = t & 63;
    const int wv = t >> 6;     // 0..3
    const int wr = wv >> 1;    // wave row-half
    const int wc = wv & 1;     // wave col-half
    const int m = lane & 31;   // frag m,n index (32-row)
    const int kh = lane >> 5;  // frag k-slot parity

    // staging sources: call c covers rows c*32..c*32+31
    const int srl = t >> 3;  // 0..31
    const int s8 = t & 7;
    const unsigned char* aSrc[4];
    const unsigned char* bSrc[4];
#pragma unroll
    for (int c = 0; c < 4; ++c) {
        const int rl = c * 32 + srl;
        const int sg = s8 ^ ((rl >> 1) & 7);
        aSrc[c] = rep + (size_t)(rb * 128 + rl) * DIM + sg * 16;
        bSrc[c] = rep + (size_t)(cb * 128 + rl) * DIM + sg * 16;
    }

    // fragment read bases (k-invariant): row wr*64 + mi*32 + m, 128 B rows;
    // swizzle fsw = (m>>1)&7 (wr/mi terms are ≡0 mod 8 after >>1).
    const int fsw = (m >> 1) & 7;
    const unsigned char* aFb = As + (wr * 64 + m) * 128;
    const unsigned char* bFb = Bs + (wc * 64 + m) * 128;

    f32x16 acc[2][2];
#pragma unroll
    for (int i = 0; i < 2; ++i)
#pragma unroll
        for (int j = 0; j < 2; ++j)
#pragma unroll
            for (int e = 0; e < 16; ++e) acc[i][j][e] = 0.f;

    for (int kk = 0; kk < DIM / 128; ++kk) {
        const int ko = kk * 128;
#pragma unroll
        for (int c = 0; c < 4; ++c) {
            gld_lds16(aSrc[c] + ko, As + c * 4096 + t * 16);
            gld_lds16(bSrc[c] + ko, Bs + c * 4096 + t * 16);
        }
        __syncthreads();

#pragma unroll
        for (int p = 0; p < 2; ++p) {  // K-half phase: global slots p*4..p*4+3
            lx2 af[2][2], bf[2][2];
#pragma unroll
            for (int mi = 0; mi < 2; ++mi)
#pragma unroll
                for (int r = 0; r < 2; ++r) {
                    const int off = ((p * 4 + r * 2 + kh) ^ fsw) << 4;
                    af[mi][r] = *(const lx2*)(aFb + mi * 4096 + off);
                    bf[mi][r] = *(const lx2*)(bFb + mi * 4096 + off);
                }
#pragma unroll
            for (int j = 0; j < 4; ++j) {
                const int r = j >> 1, h = j & 1;
#pragma unroll
                for (int mi = 0; mi < 2; ++mi)
#pragma unroll
                    for (int ni = 0; ni < 2; ++ni)
                        acc[mi][ni] = __builtin_amdgcn_mfma_f32_32x32x16_fp8_fp8(
                            af[mi][r][h], bf[ni][r][h], acc[mi][ni], 0, 0, 0);
            }
        }
        __syncthreads();
    }

    // Epilogue (R14-verified). 32x32 C/D layout:
    //   col = ni*32 + m, row = mi*32 + (reg&3) + 8*(reg>>2) + 4*kh.
    // Row-partials -> slot 2*cb+wc; transpose col-partials -> slot 2*rb+wr.
    // Row r of block i receives slots {2c,2c+1 : c>=i} ∪ {2c,2c+1 : c<i} = all 128, disjoint.
    float colsum[2];
    colsum[0] = 0.f;
    colsum[1] = 0.f;

#pragma unroll
    for (int mi = 0; mi < 2; ++mi) {
#pragma unroll
        for (int reg = 0; reg < 16; ++reg) {
            const int r32 = (reg & 3) + 8 * (reg >> 2) + 4 * kh;
            const int grow = rb * 128 + wr * 64 + mi * 32 + r32;
            float rs = 0.f;
#pragma unroll
            for (int ni = 0; ni < 2; ++ni) {
                const int gcol = cb * 128 + wc * 64 + ni * 32 + m;
                const float e =
                    (grow == gcol) ? 0.f : __expf(acc[mi][ni][reg] * 2.0f);  // 1/T=2
                rs += e;
                colsum[ni] += e;
            }
            rs += __shfl_xor(rs, 1);
            rs += __shfl_xor(rs, 2);
            rs += __shfl_xor(rs, 4);
            rs += __shfl_xor(rs, 8);
            rs += __shfl_xor(rs, 16);
            if (m == 0) partial[(size_t)(2 * cb + wc) * NN + grow] = rs;
        }
    }

    if (rb != cb) {
#pragma unroll
        for (int ni = 0; ni < 2; ++ni)
            colsum[ni] += __shfl_xor(colsum[ni], 32);  // fold kh -> all 64 rows
        if (kh == 0) {
#pragma unroll
            for (int ni = 0; ni < 2; ++ni)
                partial[(size_t)(2 * rb + wr) * NN + cb * 128 + wc * 64 + ni * 32 + m] =
                    colsum[ni];
        }
    }
}

// Kernel 3: per-row denom -> per-row loss -> 64 block sums. 2 threads/row.
__global__ void reduce_rows_kernel(const float* __restrict__ partial,
                                   const float* __restrict__ pos,
                                   float* __restrict__ bsum) {
    const int g = blockIdx.x * 256 + threadIdx.x;  // 64 x 256 = 16384
    const int r = g >> 1;
    const int half = g & 1;
    float s0 = 0.f, s1 = 0.f, s2 = 0.f, s3 = 0.f;
    for (int kb = half * 64; kb < half * 64 + 64; kb += 4) {
        s0 += partial[(size_t)(kb + 0) * NN + r];
        s1 += partial[(size_t)(kb + 1) * NN + r];
        s2 += partial[(size_t)(kb + 2) * NN + r];
        s3 += partial[(size_t)(kb + 3) * NN + r];
    }
    float s = (s0 + s1) + (s2 + s3);
    s += __shfl_xor(s, 1);  // both lanes of the pair hold the full row sum
    float v = __logf(s) - pos[r & (B_ROWS - 1)] * 2.0f;  // counted twice; *0.5 below
    v = wave_reduce_sum(v);
    __shared__ float red[4];
    const int lane = threadIdx.x & 63, wv = threadIdx.x >> 6;
    if (lane == 0) red[wv] = v;
    __syncthreads();
    if (threadIdx.x == 0)
        bsum[blockIdx.x] = (red[0] + red[1] + red[2] + red[3]) * 0.5f;
}

// Kernel 4: final scalar
__global__ void final_kernel(const float* __restrict__ bsum,
                             float* __restrict__ out) {
    float s = bsum[threadIdx.x];
    s = wave_reduce_sum(s);
    if (threadIdx.x == 0) out[0] = s * (1.0f / NN);
}

extern "C" void kernel_launch(void* const* d_in, const int* in_sizes, int n_in,
                              void* d_out, int out_size, void* d_ws, size_t ws_size,
                              hipStream_t stream) {
    const float* p1 = (const float*)d_in[0];
    const float* p2 = (const float*)d_in[1];
    char* ws = (char*)d_ws;
    unsigned char* rep = (unsigned char*)ws;                  // 8 MiB (fp8)
    float* partial = (float*)(ws + (size_t)8 * 1024 * 1024);  // 4 MiB (128 x 8192)
    float* pos = (float*)(ws + (size_t)12 * 1024 * 1024);     // 16 KiB
    float* bsum = (float*)(ws + (size_t)12 * 1024 * 1024 + 16384);  // 256 B
    float* out = (float*)d_out;

    norm_pos_kernel<<<1024, 256, 0, stream>>>(p1, p2, rep, pos);
    gemm_kernel<<<2080, 256, 0, stream>>>(rep, partial);
    reduce_rows_kernel<<<64, 256, 0, stream>>>(partial, pos, bsum);
    final_kernel<<<1, 64, 0, stream>>>(bsum, out);
}

// Round 16
// 140.780 us; speedup vs baseline: 1.5096x; 1.1120x over previous
//
#include <hip/hip_runtime.h>
#include <hip/hip_bf16.h>
#include <cstdint>

#define B_ROWS 4096
#define DIM 1024
#define NN 8192  // 2*B

typedef float f32x4 __attribute__((ext_vector_type(4)));
typedef long lx2 __attribute__((ext_vector_type(2)));

__device__ __forceinline__ float wave_reduce_sum(float v) {
    v += __shfl_xor(v, 1);
    v += __shfl_xor(v, 2);
    v += __shfl_xor(v, 4);
    v += __shfl_xor(v, 8);
    v += __shfl_xor(v, 16);
    v += __shfl_xor(v, 32);
    return v;
}

__device__ __forceinline__ void gld_lds16(const void* g, void* l) {
    __builtin_amdgcn_global_load_lds(
        (__attribute__((address_space(1))) void*)(uintptr_t)g,
        (__attribute__((address_space(3))) void*)l, 16, 0, 0);
}

// fp32 -> OCP e4m3fn, round-to-nearest-even. Inputs here satisfy |x| < 0.5,
// so no overflow/NaN handling needed. Subnormal cutoff at 2^-6.
__device__ __forceinline__ unsigned char f32_to_e4m3(float x) {
    unsigned int b = __float_as_uint(x);
    unsigned int sign = (b >> 24) & 0x80u;
    unsigned int ab = b & 0x7FFFFFFFu;
    unsigned int out;
    if (__uint_as_float(ab) >= 0.015625f) {
        unsigned int rb = ab + 0x7FFFFu + ((ab >> 20) & 1u);  // RNE at 3 mantissa bits
        int E = (int)(rb >> 23) - 127;
        out = (unsigned int)((E + 7) << 3) | ((rb >> 20) & 7u);
    } else {
        out = (unsigned int)rintf(__uint_as_float(ab) * 512.0f);  // subnormal, 0..8
    }
    return (unsigned char)(out | sign);
}

// Kernel 1: L2-normalize + positives, ONE WAVE PER ROW-PAIR (i of p1, i of p2).
// No LDS, no barriers.
__global__ void norm_pos_kernel(const float* __restrict__ p1,
                                const float* __restrict__ p2,
                                unsigned char* __restrict__ rep,
                                float* __restrict__ pos) {
    const int wv = threadIdx.x >> 6, lane = threadIdx.x & 63;
    const int i = blockIdx.x * 4 + wv;  // 0..4095
    const float4* ap = (const float4*)(p1 + (size_t)i * DIM);
    const float4* bp = (const float4*)(p2 + (size_t)i * DIM);
    float4 a[4], b[4];
#pragma unroll
    for (int c = 0; c < 4; ++c) { a[c] = ap[lane + 64 * c]; b[c] = bp[lane + 64 * c]; }
    float s1 = 0.f, s2 = 0.f, dp = 0.f;
#pragma unroll
    for (int c = 0; c < 4; ++c) {
        s1 += a[c].x * a[c].x + a[c].y * a[c].y + a[c].z * a[c].z + a[c].w * a[c].w;
        s2 += b[c].x * b[c].x + b[c].y * b[c].y + b[c].z * b[c].z + b[c].w * b[c].w;
        dp += a[c].x * b[c].x + a[c].y * b[c].y + a[c].z * b[c].z + a[c].w * b[c].w;
    }
    s1 = wave_reduce_sum(s1);
    s2 = wave_reduce_sum(s2);
    dp = wave_reduce_sum(dp);
    const float sc1 = rsqrtf(s1), sc2 = rsqrtf(s2);
    uchar4* o1 = (uchar4*)(rep + (size_t)i * DIM);
    uchar4* o2 = (uchar4*)(rep + (size_t)(i + B_ROWS) * DIM);
#pragma unroll
    for (int c = 0; c < 4; ++c) {
        uchar4 u1, u2;
        u1.x = f32_to_e4m3(a[c].x * sc1); u1.y = f32_to_e4m3(a[c].y * sc1);
        u1.z = f32_to_e4m3(a[c].z * sc1); u1.w = f32_to_e4m3(a[c].w * sc1);
        u2.x = f32_to_e4m3(b[c].x * sc2); u2.y = f32_to_e4m3(b[c].y * sc2);
        u2.z = f32_to_e4m3(b[c].z * sc2); u2.w = f32_to_e4m3(b[c].w * sc2);
        o1[lane + 64 * c] = u1;
        o2[lane + 64 * c] = u2;
    }
    if (lane == 0) pos[i] = dp * sc1 * sc2;
}

// Kernel 2: symmetric fused GEMM in fp8 e4m3, upper-triangle tiles (rb<=cb),
// BK=64, 2x2 waves (64x64 each, 4x4 frags of 16x16x32), with
// __launch_bounds__(256, 3) — the R12 configuration, best measured total
// (141 us; gemm 68 us, VGPR 64, occupancy 35%, zero spill).
//
// Structural plateau (8 variants bracketed): sync-staged 65-77 us | dbuf
// 65.6 | barrier-free 92.8 | no-LDS 138.5 | MX-scale spills (VGPR 232).
// Both 16- and 32-barrier K-loops measure identically -> the residual gap
// vs the ~35 us MFMA-demand floor is intrinsic to the staged K-loop family
// at HIP source level (the m97 plateau; only hand-asm interleaving breaks it).
//
// K-permutation trick: within BK=64 any k-bijection applied to both
// operands is contraction-invariant; each lane ds_read_b128's its swizzled
// 16 B slot once; low 8 B -> MFMA 0, high 8 B -> MFMA 1.
// Staging: thread t -> row t>>2, global 16B seg (t&3)^((row>>1)&3):
// per-quad one 64 B run (coalesced); LDS slot forced to t*16.
__global__ __launch_bounds__(256, 3) void gemm_kernel(const unsigned char* __restrict__ rep,
                                                      float* __restrict__ partial) {
    // rb-major triangle decode: start(rb) = 64*rb - rb*(rb-1)/2
    const int bid = blockIdx.x;
    int rb = (int)(64.5f - sqrtf(4160.25f - 2.0f * (float)bid));
    while (64 * (rb + 1) - (rb + 1) * rb / 2 <= bid) ++rb;
    while (64 * rb - rb * (rb - 1) / 2 > bid) --rb;
    const int cb = rb + (bid - (64 * rb - rb * (rb - 1) / 2));

    __shared__ __align__(16) unsigned char As[8192];  // 8 KB
    __shared__ __align__(16) unsigned char Bs[8192];  // 8 KB
    const int t = threadIdx.x;
    const int lane = t & 63;
    const int wv = t >> 6;     // 0..3
    const int wr = wv >> 1;    // wave row-half
    const int wc = wv & 1;     // wave col-half
    const int cm = lane & 15;  // frag m,n index
    const int q = lane >> 4;   // frag k-quarter

    // staging source
    const int sr = t >> 2;
    const int sg = (t & 3) ^ ((sr >> 1) & 3);
    const unsigned char* aS = rep + (size_t)(rb * 128 + sr) * DIM + sg * 16;
    const unsigned char* bS = rep + (size_t)(cb * 128 + sr) * DIM + sg * 16;
    unsigned char* aD = As + t * 16;  // HW-forced: wave-uniform base + lane*16
    unsigned char* bD = Bs + t * 16;

    // fragment read bases (k-invariant): row cm within 64-row group, slot q^fsw
    const int fsw = (cm >> 1) & 3;
    const unsigned char* aF = As + wr * 4096 + cm * 64 + ((q ^ fsw) << 4);
    const unsigned char* bF = Bs + wc * 4096 + cm * 64 + ((q ^ fsw) << 4);

    f32x4 acc[4][4];
#pragma unroll
    for (int i = 0; i < 4; ++i)
#pragma unroll
        for (int j = 0; j < 4; ++j) acc[i][j] = (f32x4){0.f, 0.f, 0.f, 0.f};

    for (int kk = 0; kk < DIM / 64; ++kk) {
        const unsigned char* a0 = aS + kk * 64;
        const unsigned char* b0 = bS + kk * 64;
        gld_lds16(a0, aD);                            // A rows 0..63
        gld_lds16(a0 + (size_t)64 * DIM, aD + 4096);  // A rows 64..127
        gld_lds16(b0, bD);
        gld_lds16(b0 + (size_t)64 * DIM, bD + 4096);
        __syncthreads();

        lx2 af[4], bf[4];
#pragma unroll
        for (int mi = 0; mi < 4; ++mi) af[mi] = *(const lx2*)(aF + mi * 1024);
#pragma unroll
        for (int ni = 0; ni < 4; ++ni) bf[ni] = *(const lx2*)(bF + ni * 1024);
#pragma unroll
        for (int h = 0; h < 2; ++h)
#pragma unroll
            for (int mi = 0; mi < 4; ++mi)
#pragma unroll
                for (int ni = 0; ni < 4; ++ni)
                    acc[mi][ni] = __builtin_amdgcn_mfma_f32_16x16x32_fp8_fp8(
                        af[mi][h], bf[ni][h], acc[mi][ni], 0, 0, 0);
        __syncthreads();
    }

    // Epilogue. C/D layout: col = wc*64 + ni*16 + cm, row = wr*64 + mi*16 + q*4 + reg.
    // Row-partials -> slot 2*cb+wc; transpose col-partials -> slot 2*rb+wr.
    // Row r of block i receives slots {2c,2c+1 : c>=i} ∪ {2c,2c+1 : c<i} = all 128, disjoint.
    float colsum[4];
#pragma unroll
    for (int ni = 0; ni < 4; ++ni) colsum[ni] = 0.f;

#pragma unroll
    for (int mi = 0; mi < 4; ++mi) {
#pragma unroll
        for (int reg = 0; reg < 4; ++reg) {
            const int grow = rb * 128 + wr * 64 + mi * 16 + (q << 2) + reg;
            float rs = 0.f;
#pragma unroll
            for (int ni = 0; ni < 4; ++ni) {
                const int gcol = cb * 128 + wc * 64 + ni * 16 + cm;
                const float e =
                    (grow == gcol) ? 0.f : __expf(acc[mi][ni][reg] * 2.0f);  // 1/T=2
                rs += e;
                colsum[ni] += e;
            }
            rs += __shfl_xor(rs, 1);
            rs += __shfl_xor(rs, 2);
            rs += __shfl_xor(rs, 4);
            rs += __shfl_xor(rs, 8);
            if (cm == 0) partial[(size_t)(2 * cb + wc) * NN + grow] = rs;
        }
    }

    if (rb != cb) {
#pragma unroll
        for (int ni = 0; ni < 4; ++ni) {
            colsum[ni] += __shfl_xor(colsum[ni], 16);  // fold q
            colsum[ni] += __shfl_xor(colsum[ni], 32);
        }
        if (q == 0) {
#pragma unroll
            for (int ni = 0; ni < 4; ++ni)
                partial[(size_t)(2 * rb + wr) * NN + cb * 128 + wc * 64 + ni * 16 + cm] =
                    colsum[ni];
        }
    }
}

// Kernel 3: per-row denom -> per-row loss -> 64 block sums. 2 threads/row.
__global__ void reduce_rows_kernel(const float* __restrict__ partial,
                                   const float* __restrict__ pos,
                                   float* __restrict__ bsum) {
    const int g = blockIdx.x * 256 + threadIdx.x;  // 64 x 256 = 16384
    const int r = g >> 1;
    const int half = g & 1;
    float s0 = 0.f, s1 = 0.f, s2 = 0.f, s3 = 0.f;
    for (int kb = half * 64; kb < half * 64 + 64; kb += 4) {
        s0 += partial[(size_t)(kb + 0) * NN + r];
        s1 += partial[(size_t)(kb + 1) * NN + r];
        s2 += partial[(size_t)(kb + 2) * NN + r];
        s3 += partial[(size_t)(kb + 3) * NN + r];
    }
    float s = (s0 + s1) + (s2 + s3);
    s += __shfl_xor(s, 1);  // both lanes of the pair hold the full row sum
    float v = __logf(s) - pos[r & (B_ROWS - 1)] * 2.0f;  // counted twice; *0.5 below
    v = wave_reduce_sum(v);
    __shared__ float red[4];
    const int lane = threadIdx.x & 63, wv = threadIdx.x >> 6;
    if (lane == 0) red[wv] = v;
    __syncthreads();
    if (threadIdx.x == 0)
        bsum[blockIdx.x] = (red[0] + red[1] + red[2] + red[3]) * 0.5f;
}

// Kernel 4: final scalar
__global__ void final_kernel(const float* __restrict__ bsum,
                             float* __restrict__ out) {
    float s = bsum[threadIdx.x];
    s = wave_reduce_sum(s);
    if (threadIdx.x == 0) out[0] = s * (1.0f / NN);
}

extern "C" void kernel_launch(void* const* d_in, const int* in_sizes, int n_in,
                              void* d_out, int out_size, void* d_ws, size_t ws_size,
                              hipStream_t stream) {
    const float* p1 = (const float*)d_in[0];
    const float* p2 = (const float*)d_in[1];
    char* ws = (char*)d_ws;
    unsigned char* rep = (unsigned char*)ws;                  // 8 MiB (fp8)
    float* partial = (float*)(ws + (size_t)8 * 1024 * 1024);  // 4 MiB (128 x 8192)
    float* pos = (float*)(ws + (size_t)12 * 1024 * 1024);     // 16 KiB
    float* bsum = (float*)(ws + (size_t)12 * 1024 * 1024 + 16384);  // 256 B
    float* out = (float*)d_out;

    norm_pos_kernel<<<1024, 256, 0, stream>>>(p1, p2, rep, pos);
    gemm_kernel<<<2080, 256, 0, stream>>>(rep, partial);
    reduce_rows_kernel<<<64, 256, 0, stream>>>(partial, pos, bsum);
    final_kernel<<<1, 64, 0, stream>>>(bsum, out);
}

// Round 17
// 136.407 us; speedup vs baseline: 1.5580x; 1.0321x over previous
//
#include <hip/hip_runtime.h>
#include <hip/hip_bf16.h>
#include <cstdint>

#define B_ROWS 4096
#define DIM 1024
#define NN 8192  // 2*B

typedef int v4i __attribute__((ext_vector_type(4)));

__device__ __forceinline__ float wave_reduce_sum(float v) {
    v += __shfl_xor(v, 1);
    v += __shfl_xor(v, 2);
    v += __shfl_xor(v, 4);
    v += __shfl_xor(v, 8);
    v += __shfl_xor(v, 16);
    v += __shfl_xor(v, 32);
    return v;
}

__device__ __forceinline__ void gld_lds16(const void* g, void* l) {
    __builtin_amdgcn_global_load_lds(
        (__attribute__((address_space(1))) void*)(uintptr_t)g,
        (__attribute__((address_space(3))) void*)l, 16, 0, 0);
}

// Kernel 1: L2-normalize + positives, ONE WAVE PER ROW-PAIR. No LDS/barriers.
// rep is SIGNED i8: round(127 * normalized). |x̂| <= ~0.16 for N(0,1) data at
// D=1024, so no clamp needed; i32 MFMA accumulation is exact.
__global__ void norm_pos_kernel(const float* __restrict__ p1,
                                const float* __restrict__ p2,
                                signed char* __restrict__ rep,
                                float* __restrict__ pos) {
    const int wv = threadIdx.x >> 6, lane = threadIdx.x & 63;
    const int i = blockIdx.x * 4 + wv;  // 0..4095
    const float4* ap = (const float4*)(p1 + (size_t)i * DIM);
    const float4* bp = (const float4*)(p2 + (size_t)i * DIM);
    float4 a[4], b[4];
#pragma unroll
    for (int c = 0; c < 4; ++c) { a[c] = ap[lane + 64 * c]; b[c] = bp[lane + 64 * c]; }
    float s1 = 0.f, s2 = 0.f, dp = 0.f;
#pragma unroll
    for (int c = 0; c < 4; ++c) {
        s1 += a[c].x * a[c].x + a[c].y * a[c].y + a[c].z * a[c].z + a[c].w * a[c].w;
        s2 += b[c].x * b[c].x + b[c].y * b[c].y + b[c].z * b[c].z + b[c].w * b[c].w;
        dp += a[c].x * b[c].x + a[c].y * b[c].y + a[c].z * b[c].z + a[c].w * b[c].w;
    }
    s1 = wave_reduce_sum(s1);
    s2 = wave_reduce_sum(s2);
    dp = wave_reduce_sum(dp);
    const float sc1 = rsqrtf(s1) * 127.0f, sc2 = rsqrtf(s2) * 127.0f;
    char4* o1 = (char4*)(rep + (size_t)i * DIM);
    char4* o2 = (char4*)(rep + (size_t)(i + B_ROWS) * DIM);
#pragma unroll
    for (int c = 0; c < 4; ++c) {
        char4 u1, u2;
        u1.x = (signed char)__float2int_rn(a[c].x * sc1);
        u1.y = (signed char)__float2int_rn(a[c].y * sc1);
        u1.z = (signed char)__float2int_rn(a[c].z * sc1);
        u1.w = (signed char)__float2int_rn(a[c].w * sc1);
        u2.x = (signed char)__float2int_rn(b[c].x * sc2);
        u2.y = (signed char)__float2int_rn(b[c].y * sc2);
        u2.z = (signed char)__float2int_rn(b[c].z * sc2);
        u2.w = (signed char)__float2int_rn(b[c].w * sc2);
        o1[lane + 64 * c] = u1;
        o2[lane + 64 * c] = u2;
    }
    if (lane == 0) pos[i] = dp * rsqrtf(s1) * rsqrtf(s2);
}

// Kernel 2: symmetric fused GEMM in i8 (mfma_i32_16x16x64_i8 — 2x the
// per-instruction K of fp8 at the same cycle cost, plain v4i operands so no
// mfma_scale register blow-up). Upper-triangle tiles (rb<=cb), BK=64,
// 2x2 waves (64x64 each, 4x4 frags), __launch_bounds__(256,3) — the
// R12/R16 measured-best envelope (VGPR 64, occ 32%, 0 conflicts).
// vs R16: IDENTICAL staging and ds_read_b128 count, HALF the MFMA
// instructions (16/iter/wave) — attacks the 46%-of-cycles MFMA term.
//
// K-perm trick: each lane reads its swizzled 16 B slot once; A-lane (m,q)
// and B-lane (n,q) hold the same 16 global-k bytes in the same order, so
// the HW pairs element j with element j at equal k — contraction invariant.
// Staging: thread t -> row t>>2, global 16B seg (t&3)^((row>>1)&3):
// per-quad one 64 B run (coalesced); LDS slot forced to t*16.
__global__ __launch_bounds__(256, 3) void gemm_kernel(const signed char* __restrict__ rep,
                                                      float* __restrict__ partial) {
    // rb-major triangle decode: start(rb) = 64*rb - rb*(rb-1)/2
    const int bid = blockIdx.x;
    int rb = (int)(64.5f - sqrtf(4160.25f - 2.0f * (float)bid));
    while (64 * (rb + 1) - (rb + 1) * rb / 2 <= bid) ++rb;
    while (64 * rb - rb * (rb - 1) / 2 > bid) --rb;
    const int cb = rb + (bid - (64 * rb - rb * (rb - 1) / 2));

    __shared__ __align__(16) signed char As[8192];  // 8 KB
    __shared__ __align__(16) signed char Bs[8192];  // 8 KB
    const int t = threadIdx.x;
    const int lane = t & 63;
    const int wv = t >> 6;     // 0..3
    const int wr = wv >> 1;    // wave row-half
    const int wc = wv & 1;     // wave col-half
    const int cm = lane & 15;  // frag m,n index
    const int q = lane >> 4;   // frag k-quarter

    // staging source
    const int sr = t >> 2;
    const int sg = (t & 3) ^ ((sr >> 1) & 3);
    const signed char* aS = rep + (size_t)(rb * 128 + sr) * DIM + sg * 16;
    const signed char* bS = rep + (size_t)(cb * 128 + sr) * DIM + sg * 16;
    signed char* aD = As + t * 16;  // HW-forced: wave-uniform base + lane*16
    signed char* bD = Bs + t * 16;

    // fragment read bases (k-invariant): row cm within 64-row group, slot q^fsw
    const int fsw = (cm >> 1) & 3;
    const signed char* aF = As + wr * 4096 + cm * 64 + ((q ^ fsw) << 4);
    const signed char* bF = Bs + wc * 4096 + cm * 64 + ((q ^ fsw) << 4);

    v4i acc[4][4];
#pragma unroll
    for (int i = 0; i < 4; ++i)
#pragma unroll
        for (int j = 0; j < 4; ++j) acc[i][j] = (v4i){0, 0, 0, 0};

    for (int kk = 0; kk < DIM / 64; ++kk) {
        const signed char* a0 = aS + kk * 64;
        const signed char* b0 = bS + kk * 64;
        gld_lds16(a0, aD);                            // A rows 0..63
        gld_lds16(a0 + (size_t)64 * DIM, aD + 4096);  // A rows 64..127
        gld_lds16(b0, bD);
        gld_lds16(b0 + (size_t)64 * DIM, bD + 4096);
        __syncthreads();

        v4i af[4], bf[4];
#pragma unroll
        for (int mi = 0; mi < 4; ++mi) af[mi] = *(const v4i*)(aF + mi * 1024);
#pragma unroll
        for (int ni = 0; ni < 4; ++ni) bf[ni] = *(const v4i*)(bF + ni * 1024);
#pragma unroll
        for (int mi = 0; mi < 4; ++mi)
#pragma unroll
            for (int ni = 0; ni < 4; ++ni)
                acc[mi][ni] = __builtin_amdgcn_mfma_i32_16x16x64_i8(
                    af[mi], bf[ni], acc[mi][ni], 0, 0, 0);
        __syncthreads();
    }

    // Epilogue. C/D layout: col = wc*64 + ni*16 + cm, row = wr*64 + mi*16 + q*4 + reg.
    // sim = acc / 127^2; exp(sim * 2). Row-partials -> slot 2*cb+wc;
    // transpose col-partials -> slot 2*rb+wr. Row r of block i receives
    // slots {2c,2c+1 : c>=i} ∪ {2c,2c+1 : c<i} = all 128, disjoint.
    const float esc = 2.0f / 16129.0f;  // (1/T) / 127^2
    float colsum[4];
#pragma unroll
    for (int ni = 0; ni < 4; ++ni) colsum[ni] = 0.f;

#pragma unroll
    for (int mi = 0; mi < 4; ++mi) {
#pragma unroll
        for (int reg = 0; reg < 4; ++reg) {
            const int grow = rb * 128 + wr * 64 + mi * 16 + (q << 2) + reg;
            float rs = 0.f;
#pragma unroll
            for (int ni = 0; ni < 4; ++ni) {
                const int gcol = cb * 128 + wc * 64 + ni * 16 + cm;
                const float e =
                    (grow == gcol) ? 0.f : __expf((float)acc[mi][ni][reg] * esc);
                rs += e;
                colsum[ni] += e;
            }
            rs += __shfl_xor(rs, 1);
            rs += __shfl_xor(rs, 2);
            rs += __shfl_xor(rs, 4);
            rs += __shfl_xor(rs, 8);
            if (cm == 0) partial[(size_t)(2 * cb + wc) * NN + grow] = rs;
        }
    }

    if (rb != cb) {
#pragma unroll
        for (int ni = 0; ni < 4; ++ni) {
            colsum[ni] += __shfl_xor(colsum[ni], 16);  // fold q
            colsum[ni] += __shfl_xor(colsum[ni], 32);
        }
        if (q == 0) {
#pragma unroll
            for (int ni = 0; ni < 4; ++ni)
                partial[(size_t)(2 * rb + wr) * NN + cb * 128 + wc * 64 + ni * 16 + cm] =
                    colsum[ni];
        }
    }
}

// Kernel 3: per-row denom -> per-row loss -> 64 block sums. 2 threads/row.
__global__ void reduce_rows_kernel(const float* __restrict__ partial,
                                   const float* __restrict__ pos,
                                   float* __restrict__ bsum) {
    const int g = blockIdx.x * 256 + threadIdx.x;  // 64 x 256 = 16384
    const int r = g >> 1;
    const int half = g & 1;
    float s0 = 0.f, s1 = 0.f, s2 = 0.f, s3 = 0.f;
    for (int kb = half * 64; kb < half * 64 + 64; kb += 4) {
        s0 += partial[(size_t)(kb + 0) * NN + r];
        s1 += partial[(size_t)(kb + 1) * NN + r];
        s2 += partial[(size_t)(kb + 2) * NN + r];
        s3 += partial[(size_t)(kb + 3) * NN + r];
    }
    float s = (s0 + s1) + (s2 + s3);
    s += __shfl_xor(s, 1);  // both lanes of the pair hold the full row sum
    float v = __logf(s) - pos[r & (B_ROWS - 1)] * 2.0f;  // counted twice; *0.5 below
    v = wave_reduce_sum(v);
    __shared__ float red[4];
    const int lane = threadIdx.x & 63, wv = threadIdx.x >> 6;
    if (lane == 0) red[wv] = v;
    __syncthreads();
    if (threadIdx.x == 0)
        bsum[blockIdx.x] = (red[0] + red[1] + red[2] + red[3]) * 0.5f;
}

// Kernel 4: final scalar
__global__ void final_kernel(const float* __restrict__ bsum,
                             float* __restrict__ out) {
    float s = bsum[threadIdx.x];
    s = wave_reduce_sum(s);
    if (threadIdx.x == 0) out[0] = s * (1.0f / NN);
}

extern "C" void kernel_launch(void* const* d_in, const int* in_sizes, int n_in,
                              void* d_out, int out_size, void* d_ws, size_t ws_size,
                              hipStream_t stream) {
    const float* p1 = (const float*)d_in[0];
    const float* p2 = (const float*)d_in[1];
    char* ws = (char*)d_ws;
    signed char* rep = (signed char*)ws;                      // 8 MiB (i8)
    float* partial = (float*)(ws + (size_t)8 * 1024 * 1024);  // 4 MiB (128 x 8192)
    float* pos = (float*)(ws + (size_t)12 * 1024 * 1024);     // 16 KiB
    float* bsum = (float*)(ws + (size_t)12 * 1024 * 1024 + 16384);  // 256 B
    float* out = (float*)d_out;

    norm_pos_kernel<<<1024, 256, 0, stream>>>(p1, p2, rep, pos);
    gemm_kernel<<<2080, 256, 0, stream>>>(rep, partial);
    reduce_rows_kernel<<<64, 256, 0, stream>>>(partial, pos, bsum);
    final_kernel<<<1, 64, 0, stream>>>(bsum, out);
}